// Round 8
// baseline (1024.454 us; speedup 1.0000x reference)
//
#include <hip/hip_runtime.h>

typedef unsigned short u16;
typedef unsigned int   u32;
typedef short  bf16x8 __attribute__((ext_vector_type(8)));
typedef float  f32x4  __attribute__((ext_vector_type(4)));

#define T_SEQ 256
#define BATCH 1024
#define HID   128

__device__ __forceinline__ u16 f2bf(float f) {
  u32 x = __builtin_bit_cast(u32, f);
  x = x + 0x7fffu + ((x >> 16) & 1u);   // round-to-nearest-even
  return (u16)(x >> 16);
}
__device__ __forceinline__ float sigm(float x) {
  return __builtin_amdgcn_rcpf(1.0f + __expf(-x));
}
__device__ __forceinline__ float tanh_f(float x) {
  return 2.0f * __builtin_amdgcn_rcpf(1.0f + __expf(-2.0f * x)) - 1.0f;
}

// ---------------------------------------------------------------------------
// Convert x_in fp32 -> bf16 (4/thread) + zero the 64 producer->consumer flags.
// ---------------------------------------------------------------------------
__global__ void conv_x_kernel(const float* __restrict__ x_in, u16* __restrict__ xb,
                              u32* __restrict__ flags) {
  if (blockIdx.x == 0 && threadIdx.x < 64) flags[threadIdx.x] = 0;
  int i = (blockIdx.x * blockDim.x + threadIdx.x) * 4;
  float4 v = *(const float4*)(x_in + i);
  u32 lo = (u32)f2bf(v.x) | ((u32)f2bf(v.y) << 16);
  u32 hi = (u32)f2bf(v.z) | ((u32)f2bf(v.w) << 16);
  *(u32*)(xb + i) = lo;
  *(u32*)(xb + i + 2) = hi;
}

// ---------------------------------------------------------------------------
// Prep (PERMUTED gate layout — compute-validated R2-R4).
// Wave n owns h-cols [n*8,n*8+8): tile0 = i|f halves, tile1 = g|o halves.
//   col=lane&15, quad=lane>>4, gate t = tile*2+(col>>3), j=col&7
//   orig row r = t*128 + n*8 + j ; k = kk*32 + quad*8 + e
// WcP = w_ih0 @ pre_w (K=64, KK=2); bias0 = w_ih0@pre_b + b_ih0 + b_hh0.
// ---------------------------------------------------------------------------
__global__ void prep_kernel(const float* __restrict__ pre_w, const float* __restrict__ pre_b,
                            const float* __restrict__ w_ih0, const float* __restrict__ w_hh0,
                            const float* __restrict__ b_ih0, const float* __restrict__ b_hh0,
                            const float* __restrict__ w_ih1, const float* __restrict__ w_hh1,
                            const float* __restrict__ b_ih1, const float* __restrict__ b_hh1,
                            u16* __restrict__ WcP, u16* __restrict__ WhhP0,
                            u16* __restrict__ WihP1, u16* __restrict__ WhhP1,
                            float* __restrict__ bias0, float* __restrict__ bias1) {
  const int TOT = 230400;
  for (int idx = blockIdx.x * blockDim.x + threadIdx.x; idx < TOT;
       idx += gridDim.x * blockDim.x) {
    if (idx < 32768) {                       // WcP (KK=2)
      int e = idx & 7, lane = (idx >> 3) & 63, kk = (idx >> 9) & 1,
          tile = (idx >> 10) & 1, n = idx >> 11;
      int col = lane & 15, quad = lane >> 4;
      int r = (tile * 2 + (col >> 3)) * 128 + n * 8 + (col & 7);
      int k = kk * 32 + quad * 8 + e;
      float s = 0.f;
      for (int h = 0; h < 128; ++h)
        s += w_ih0[r * 128 + h] * pre_w[h * 64 + k];
      WcP[idx] = f2bf(s);
    } else if (idx < 33280) {                // bias0 permuted (fp32)
      int p = idx - 32768;
      int col = p & 15, tile = (p >> 4) & 1, n = p >> 5;
      int r = (tile * 2 + (col >> 3)) * 128 + n * 8 + (col & 7);
      float s = b_ih0[r] + b_hh0[r];
      for (int h = 0; h < 128; ++h)
        s += w_ih0[r * 128 + h] * pre_b[h];
      bias0[p] = s;
    } else if (idx < 229888) {               // 3 permuted bf16 copies (KK=4)
      int q = idx - 33280;
      int mat = q / 65536; q = q % 65536;
      int e = q & 7, lane = (q >> 3) & 63, kk = (q >> 9) & 3,
          tile = (q >> 11) & 1, n = q >> 12;
      int col = lane & 15, quad = lane >> 4;
      int r = (tile * 2 + (col >> 3)) * 128 + n * 8 + (col & 7);
      int k = kk * 32 + quad * 8 + e;
      const float* src = mat == 0 ? w_hh0 : (mat == 1 ? w_ih1 : w_hh1);
      u16* dst = mat == 0 ? WhhP0 : (mat == 1 ? WihP1 : WhhP1);
      dst[q] = f2bf(src[r * 128 + k]);
    } else {                                 // bias1 permuted (fp32)
      int p = idx - 229888;
      int col = p & 15, tile = (p >> 4) & 1, n = p >> 5;
      int r = (tile * 2 + (col >> 3)) * 128 + n * 8 + (col & 7);
      bias1[p] = b_ih1[r] + b_hh1[r];
    }
  }
}

// ---------------------------------------------------------------------------
// Fused pipelined 2-layer LSTM. 128 WGs: role = bid>>6 (0=L0 producer,
// 1=L1 consumer), blk = bid&63, 16 batch rows each. Weight-stationary
// (launch_bounds(1024,4)). Steady-state has NO cache maintenance:
//  * y0 stores = relaxed agent atomic u32 (write-through to L3, no L2 alloc)
//  * flag = RELEASE store of t after barrier t (stores of step t-1 drained
//    by that barrier across ALL waves -> race-free, one-step-late)
//  * consumer polls flag with RELAXED agent atomic load (no L2 inv);
//    y0 data lines are first-touch per step -> plain b128 loads are fresh
//  * producer prefetches x(t+1) into registers mid-step
// ---------------------------------------------------------------------------
template <int KKI, bool PROD>
__device__ __forceinline__ void scan_role(
    const u16* __restrict__ xsrc, const u16* __restrict__ WihF,
    const u16* __restrict__ WhhF, const float* __restrict__ biasP,
    const float* __restrict__ h0_in, const float* __restrict__ c0_in,
    u16* __restrict__ y_out, u32* flag, float* __restrict__ dout,
    const float* __restrict__ post_w, const float* __restrict__ post_b,
    int b0, u32 (*hbuf)[1024], float (*h32)[130]) {
  constexpr int KIN = KKI * 32;
  constexpr int LAYER = PROD ? 0 : 1;
  const int tid = threadIdx.x, wave = tid >> 6, lane = tid & 63;
  const int col = lane & 15, quad = lane >> 4;

  bf16x8 wih[2][KKI], whh[2][4];
#pragma unroll
  for (int t2 = 0; t2 < 2; ++t2)
#pragma unroll
    for (int kk = 0; kk < KKI; ++kk)
      wih[t2][kk] = *(const bf16x8*)(WihF + (((wave * 2 + t2) * KKI + kk) * 64 + lane) * 8);
#pragma unroll
  for (int t2 = 0; t2 < 2; ++t2)
#pragma unroll
    for (int kk = 0; kk < 4; ++kk)
      whh[t2][kk] = *(const bf16x8*)(WhhF + (((wave * 2 + t2) * 4 + kk) * 64 + lane) * 8);
  const float bias_t0 = biasP[wave * 32 + col];
  const float bias_t1 = biasP[wave * 32 + 16 + col];

  const int hi = col >> 3;          // lo lanes finish rows 0,1; hi lanes rows 2,3
  const int rbase = hi * 2;
  const int jcol = wave * 8 + (col & 7);

  float cst[2], hf[2];
#pragma unroll
  for (int rr = 0; rr < 2; ++rr) {
    cst[rr] = c0_in[(LAYER * BATCH + b0 + quad * 4 + rbase + rr) * HID + jcol];
    hf[rr]  = h0_in[(LAYER * BATCH + b0 + quad * 4 + rbase + rr) * HID + jcol];
  }

  {  // init hbuf[0] = h0 (swizzled bf16)
    const float* src = h0_in + (LAYER * BATCH + b0 + wave) * HID + lane * 2;
    u32 v = (u32)f2bf(src[0]) | ((u32)f2bf(src[1]) << 16);
    hbuf[0][wave * 64 + (((lane >> 2) ^ wave) << 2) + (lane & 3)] = v;
  }
  __syncthreads();

  const u16* xrow = xsrc + (b0 + col) * KIN;

  bf16x8 axp[KKI];                 // producer: prefetched x-fragments for step t
  if (PROD) {
#pragma unroll
    for (int kk = 0; kk < KKI; ++kk)
      axp[kk] = *(const bf16x8*)(xrow + kk * 32 + quad * 8);
  }

  for (int t = 0; t < T_SEQ; ++t) {
    const int cb = t & 1, nb = (t + 1) & 1;
    if (!PROD) {
      if (tid == 0) {
        while (__hip_atomic_load(flag, __ATOMIC_RELAXED, __HIP_MEMORY_SCOPE_AGENT) <
               (u32)(t + 1))
          __builtin_amdgcn_s_sleep(2);
      }
      __syncthreads();   // all waves held until flag >= t+1
    }
    bf16x8 ax[KKI], ah[4];
    if (PROD) {
#pragma unroll
      for (int kk = 0; kk < KKI; ++kk) ax[kk] = axp[kk];
    } else {
#pragma unroll
      for (int kk = 0; kk < KKI; ++kk)
        ax[kk] = *(const bf16x8*)(xrow + kk * 32 + quad * 8);
    }
#pragma unroll
    for (int kk = 0; kk < 4; ++kk)
      ah[kk] = *(const bf16x8*)((const char*)&hbuf[cb][0] + col * 256 +
                                (((kk * 4 + quad) ^ col) << 4));
    f32x4 acc0 = {bias_t0, bias_t0, bias_t0, bias_t0};
    f32x4 acc1 = {bias_t1, bias_t1, bias_t1, bias_t1};
#pragma unroll
    for (int kk = 0; kk < KKI; ++kk) {
      acc0 = __builtin_amdgcn_mfma_f32_16x16x32_bf16(ax[kk], wih[0][kk], acc0, 0, 0, 0);
      acc1 = __builtin_amdgcn_mfma_f32_16x16x32_bf16(ax[kk], wih[1][kk], acc1, 0, 0, 0);
    }
    if (PROD && t + 1 < T_SEQ) {   // prefetch x(t+1) — hidden behind whh+pointwise
      const u16* xn = xrow + BATCH * KIN;
#pragma unroll
      for (int kk = 0; kk < KKI; ++kk)
        axp[kk] = *(const bf16x8*)(xn + kk * 32 + quad * 8);
    }
#pragma unroll
    for (int kk = 0; kk < 4; ++kk) {
      acc0 = __builtin_amdgcn_mfma_f32_16x16x32_bf16(ah[kk], whh[0][kk], acc0, 0, 0, 0);
      acc1 = __builtin_amdgcn_mfma_f32_16x16x32_bf16(ah[kk], whh[1][kk], acc1, 0, 0, 0);
    }
    // validated exchange: lo lanes finish rows {0,1}, hi lanes {2,3}
#pragma unroll
    for (int rr = 0; rr < 2; ++rr) {
      float a_lo0 = acc0[rr], a_hi0 = acc0[2 + rr];
      float a_lo1 = acc1[rr], a_hi1 = acc1[2 + rr];
      float send0 = hi ? a_lo0 : a_hi0;
      float send1 = hi ? a_lo1 : a_hi1;
      float recv0 = __shfl_xor(send0, 8, 64);
      float recv1 = __shfl_xor(send1, 8, 64);
      float keep0 = hi ? a_hi0 : a_lo0;
      float keep1 = hi ? a_hi1 : a_lo1;
      float iv = hi ? recv0 : keep0;
      float fv = hi ? keep0 : recv0;
      float gv = hi ? recv1 : keep1;
      float ov = hi ? keep1 : recv1;
      float si = sigm(iv), sf = sigm(fv), tg = tanh_f(gv), so = sigm(ov);
      float cn = sf * cst[rr] + si * tg;
      cst[rr] = cn;
      hf[rr] = so * tanh_f(cn);
      int m = quad * 4 + rbase + rr;
      *(u16*)((char*)&hbuf[nb][0] + m * 256 + ((wave ^ m) << 4) + (col & 7) * 2) =
          f2bf(hf[rr]);
    }
    __syncthreads();
    if (PROD) {
      u32 v = hbuf[nb][wave * 64 + (((lane >> 2) ^ wave) << 2) + (lane & 3)];
      // write-through (agent-scope, no L2 allocate) so consumer's first-touch
      // b128 loads see fresh data without any invalidate
      __hip_atomic_store((u32*)(y_out + (t * BATCH + b0 + wave) * HID + lane * 2), v,
                         __ATOMIC_RELAXED, __HIP_MEMORY_SCOPE_AGENT);
      // one-step-late publish: barrier t drained ALL waves' stores of step t-1
      if (tid == 0 && t)
        __hip_atomic_store(flag, (u32)t, __ATOMIC_RELEASE, __HIP_MEMORY_SCOPE_AGENT);
    }
    xrow += BATCH * KIN;
  }
  if (PROD) {
    __syncthreads();   // drain final y stores
    if (tid == 0)
      __hip_atomic_store(flag, (u32)T_SEQ, __ATOMIC_RELEASE, __HIP_MEMORY_SCOPE_AGENT);
  }

  // ---- finals from fp32 registers ----
#pragma unroll
  for (int rr = 0; rr < 2; ++rr) {
    int m = quad * 4 + rbase + rr;
    dout[BATCH + LAYER * (BATCH * HID) + (b0 + m) * HID + jcol] = hf[rr];
    dout[BATCH + 2 * BATCH * HID + LAYER * (BATCH * HID) + (b0 + m) * HID + jcol] = cst[rr];
  }

  if (!PROD) {  // pred via fp32 LDS stage
#pragma unroll
    for (int rr = 0; rr < 2; ++rr)
      h32[quad * 4 + rbase + rr][jcol] = hf[rr];
    __syncthreads();
    float a0 = fmaxf(h32[wave][2 * lane], 0.f);
    float a1 = fmaxf(h32[wave][2 * lane + 1], 0.f);
    float p = a0 * post_w[2 * lane] + a1 * post_w[2 * lane + 1];
#pragma unroll
    for (int off = 32; off > 0; off >>= 1) p += __shfl_down(p, off, 64);
    if (lane == 0) dout[b0 + wave] = p + post_b[0];
  }
}

__global__ __launch_bounds__(1024, 4) void lstm_fused(
    const u16* __restrict__ xb,
    const u16* __restrict__ WcP, const u16* __restrict__ WhhP0,
    const float* __restrict__ bias0,
    const u16* __restrict__ WihP1, const u16* __restrict__ WhhP1,
    const float* __restrict__ bias1,
    const float* __restrict__ h0_in, const float* __restrict__ c0_in,
    u16* __restrict__ y0, u32* __restrict__ flags, float* __restrict__ dout,
    const float* __restrict__ post_w, const float* __restrict__ post_b) {
  __shared__ __align__(16) u32 hbuf[2][1024];
  __shared__ float h32[16][130];
  const int role = blockIdx.x >> 6;      // pairs (L0 b, L1 b) land on same XCD (64%8==0)
  const int blk = blockIdx.x & 63;
  const int b0 = blk * 16;
  if (role == 0)
    scan_role<2, true>(xb, WcP, WhhP0, bias0, h0_in, c0_in, y0, &flags[blk], dout,
                       post_w, post_b, b0, hbuf, h32);
  else
    scan_role<4, false>(y0, WihP1, WhhP1, bias1, h0_in, c0_in, y0, &flags[blk], dout,
                        post_w, post_b, b0, hbuf, h32);
}

extern "C" void kernel_launch(void* const* d_in, const int* in_sizes, int n_in,
                              void* d_out, int out_size, void* d_ws, size_t ws_size,
                              hipStream_t stream) {
  const float* x_in  = (const float*)d_in[0];
  const float* h0    = (const float*)d_in[1];
  const float* c0    = (const float*)d_in[2];
  const float* pre_w = (const float*)d_in[3];
  const float* pre_b = (const float*)d_in[4];
  const float* w_ih0 = (const float*)d_in[5];
  const float* w_hh0 = (const float*)d_in[6];
  const float* b_ih0 = (const float*)d_in[7];
  const float* b_hh0 = (const float*)d_in[8];
  const float* w_ih1 = (const float*)d_in[9];
  const float* w_hh1 = (const float*)d_in[10];
  const float* b_ih1 = (const float*)d_in[11];
  const float* b_hh1 = (const float*)d_in[12];
  const float* post_w = (const float*)d_in[13];
  const float* post_b = (const float*)d_in[14];
  float* out = (float*)d_out;
  char* ws = (char*)d_ws;

  u16*   WcP   = (u16*)(ws + 0);        // 65536 B
  u16*   WhhP0 = (u16*)(ws + 65536);    // 131072 B
  u16*   WihP1 = (u16*)(ws + 196608);   // 131072 B
  u16*   WhhP1 = (u16*)(ws + 327680);   // 131072 B
  float* bias0 = (float*)(ws + 458752); // 2048 B
  float* bias1 = (float*)(ws + 460800); // 2048 B
  u32*   flags = (u32*)(ws + 462848);   // 256 B
  u16*   xb    = (u16*)(ws + 463104);   // 33554432 B
  u16*   y0    = (u16*)(ws + 34017536); // 67108864 B

  conv_x_kernel<<<dim3(16384), dim3(256), 0, stream>>>(x_in, xb, flags);
  prep_kernel<<<dim3(256), dim3(256), 0, stream>>>(
      pre_w, pre_b, w_ih0, w_hh0, b_ih0, b_hh0, w_ih1, w_hh1, b_ih1, b_hh1,
      WcP, WhhP0, WihP1, WhhP1, bias0, bias1);
  lstm_fused<<<dim3(128), dim3(1024), 0, stream>>>(
      xb, WcP, WhhP0, bias0, WihP1, WhhP1, bias1, h0, c0, y0, flags, out,
      post_w, post_b);
}

// Round 9
// 763.568 us; speedup vs baseline: 1.3417x; 1.3417x over previous
//
#include <hip/hip_runtime.h>

typedef unsigned short u16;
typedef unsigned int   u32;
typedef short  bf16x8 __attribute__((ext_vector_type(8)));
typedef float  f32x4  __attribute__((ext_vector_type(4)));

#define T_SEQ 256
#define BATCH 1024
#define HID   128

__device__ __forceinline__ u16 f2bf(float f) {
  u32 x = __builtin_bit_cast(u32, f);
  x = x + 0x7fffu + ((x >> 16) & 1u);   // round-to-nearest-even
  return (u16)(x >> 16);
}
__device__ __forceinline__ float sigm(float x) {
  return __builtin_amdgcn_rcpf(1.0f + __expf(-x));
}
__device__ __forceinline__ float tanh_f(float x) {
  return 2.0f * __builtin_amdgcn_rcpf(1.0f + __expf(-2.0f * x)) - 1.0f;
}

// ---------------------------------------------------------------------------
// Convert x_in fp32 -> bf16 (4/thread) + zero the 64 producer->consumer flags.
// ---------------------------------------------------------------------------
__global__ void conv_x_kernel(const float* __restrict__ x_in, u16* __restrict__ xb,
                              u32* __restrict__ flags) {
  if (blockIdx.x == 0 && threadIdx.x < 64) flags[threadIdx.x] = 0;
  int i = (blockIdx.x * blockDim.x + threadIdx.x) * 4;
  float4 v = *(const float4*)(x_in + i);
  u32 lo = (u32)f2bf(v.x) | ((u32)f2bf(v.y) << 16);
  u32 hi = (u32)f2bf(v.z) | ((u32)f2bf(v.w) << 16);
  *(u32*)(xb + i) = lo;
  *(u32*)(xb + i + 2) = hi;
}

// ---------------------------------------------------------------------------
// Prep (PERMUTED gate layout — compute-validated R2-R4).
// Wave n owns h-cols [n*8,n*8+8): tile0 = i|f halves, tile1 = g|o halves.
//   col=lane&15, quad=lane>>4, gate t = tile*2+(col>>3), j=col&7
//   orig row r = t*128 + n*8 + j ; k = kk*32 + quad*8 + e
// WcP = w_ih0 @ pre_w (K=64, KK=2); bias0 = w_ih0@pre_b + b_ih0 + b_hh0.
// ---------------------------------------------------------------------------
__global__ void prep_kernel(const float* __restrict__ pre_w, const float* __restrict__ pre_b,
                            const float* __restrict__ w_ih0, const float* __restrict__ w_hh0,
                            const float* __restrict__ b_ih0, const float* __restrict__ b_hh0,
                            const float* __restrict__ w_ih1, const float* __restrict__ w_hh1,
                            const float* __restrict__ b_ih1, const float* __restrict__ b_hh1,
                            u16* __restrict__ WcP, u16* __restrict__ WhhP0,
                            u16* __restrict__ WihP1, u16* __restrict__ WhhP1,
                            float* __restrict__ bias0, float* __restrict__ bias1) {
  const int TOT = 230400;
  for (int idx = blockIdx.x * blockDim.x + threadIdx.x; idx < TOT;
       idx += gridDim.x * blockDim.x) {
    if (idx < 32768) {                       // WcP (KK=2)
      int e = idx & 7, lane = (idx >> 3) & 63, kk = (idx >> 9) & 1,
          tile = (idx >> 10) & 1, n = idx >> 11;
      int col = lane & 15, quad = lane >> 4;
      int r = (tile * 2 + (col >> 3)) * 128 + n * 8 + (col & 7);
      int k = kk * 32 + quad * 8 + e;
      float s = 0.f;
      for (int h = 0; h < 128; ++h)
        s += w_ih0[r * 128 + h] * pre_w[h * 64 + k];
      WcP[idx] = f2bf(s);
    } else if (idx < 33280) {                // bias0 permuted (fp32)
      int p = idx - 32768;
      int col = p & 15, tile = (p >> 4) & 1, n = p >> 5;
      int r = (tile * 2 + (col >> 3)) * 128 + n * 8 + (col & 7);
      float s = b_ih0[r] + b_hh0[r];
      for (int h = 0; h < 128; ++h)
        s += w_ih0[r * 128 + h] * pre_b[h];
      bias0[p] = s;
    } else if (idx < 229888) {               // 3 permuted bf16 copies (KK=4)
      int q = idx - 33280;
      int mat = q / 65536; q = q % 65536;
      int e = q & 7, lane = (q >> 3) & 63, kk = (q >> 9) & 3,
          tile = (q >> 11) & 1, n = q >> 12;
      int col = lane & 15, quad = lane >> 4;
      int r = (tile * 2 + (col >> 3)) * 128 + n * 8 + (col & 7);
      int k = kk * 32 + quad * 8 + e;
      const float* src = mat == 0 ? w_hh0 : (mat == 1 ? w_ih1 : w_hh1);
      u16* dst = mat == 0 ? WhhP0 : (mat == 1 ? WihP1 : WhhP1);
      dst[q] = f2bf(src[r * 128 + k]);
    } else {                                 // bias1 permuted (fp32)
      int p = idx - 229888;
      int col = p & 15, tile = (p >> 4) & 1, n = p >> 5;
      int r = (tile * 2 + (col >> 3)) * 128 + n * 8 + (col & 7);
      bias1[p] = b_ih1[r] + b_hh1[r];
    }
  }
}

// ---------------------------------------------------------------------------
// Fused pipelined 2-layer LSTM. 128 WGs: role = bid>>6 (0=L0 producer,
// 1=L1 consumer), blk = bid&63, 16 batch rows each. Weight-stationary
// (launch_bounds(1024,4) -> 128 VGPR/wave incl. AGPR half).
//  * y0 stores: plain coalesced u32 (R7-proven; R8's atomic stores regressed)
//  * producer publishes flag=t+1 at t%4==3 with RELEASE (wbL2 1x/4 steps,
//    issued by tid0 after the barrier -> overlapped by other waves' next step)
//  * consumer polls with ACQUIRE only at t%4==0, requiring flag>=min(t+8,256)
//    (2 publish-batches ahead); the group-start acquire covers all y0 lines
//    read in the group (tightest line published >=6 steps ~19us before read)
//  * both roles prefetch x(t+1) IN-PLACE into ax after the wih MFMAs consume
//    it (zero VGPR growth), hiding L3 latency behind whh MFMAs + pointwise
// ---------------------------------------------------------------------------
template <int KKI, bool PROD>
__device__ __forceinline__ void scan_role(
    const u16* __restrict__ xsrc, const u16* __restrict__ WihF,
    const u16* __restrict__ WhhF, const float* __restrict__ biasP,
    const float* __restrict__ h0_in, const float* __restrict__ c0_in,
    u16* __restrict__ y_out, u32* flag, float* __restrict__ dout,
    const float* __restrict__ post_w, const float* __restrict__ post_b,
    int b0, u32 (*hbuf)[1024], float (*h32)[130]) {
  constexpr int KIN = KKI * 32;
  constexpr int LAYER = PROD ? 0 : 1;
  const int tid = threadIdx.x, wave = tid >> 6, lane = tid & 63;
  const int col = lane & 15, quad = lane >> 4;

  bf16x8 wih[2][KKI], whh[2][4];
#pragma unroll
  for (int t2 = 0; t2 < 2; ++t2)
#pragma unroll
    for (int kk = 0; kk < KKI; ++kk)
      wih[t2][kk] = *(const bf16x8*)(WihF + (((wave * 2 + t2) * KKI + kk) * 64 + lane) * 8);
#pragma unroll
  for (int t2 = 0; t2 < 2; ++t2)
#pragma unroll
    for (int kk = 0; kk < 4; ++kk)
      whh[t2][kk] = *(const bf16x8*)(WhhF + (((wave * 2 + t2) * 4 + kk) * 64 + lane) * 8);
  const float bias_t0 = biasP[wave * 32 + col];
  const float bias_t1 = biasP[wave * 32 + 16 + col];

  const int hi = col >> 3;          // lo lanes finish rows 0,1; hi lanes rows 2,3
  const int rbase = hi * 2;
  const int jcol = wave * 8 + (col & 7);

  float cst[2], hf[2];
#pragma unroll
  for (int rr = 0; rr < 2; ++rr) {
    cst[rr] = c0_in[(LAYER * BATCH + b0 + quad * 4 + rbase + rr) * HID + jcol];
    hf[rr]  = h0_in[(LAYER * BATCH + b0 + quad * 4 + rbase + rr) * HID + jcol];
  }

  {  // init hbuf[0] = h0 (swizzled bf16)
    const float* src = h0_in + (LAYER * BATCH + b0 + wave) * HID + lane * 2;
    u32 v = (u32)f2bf(src[0]) | ((u32)f2bf(src[1]) << 16);
    hbuf[0][wave * 64 + (((lane >> 2) ^ wave) << 2) + (lane & 3)] = v;
  }

  if (!PROD) {  // initial sync: producer must be >= 8 steps ahead
    if (tid == 0) {
      while (__hip_atomic_load(flag, __ATOMIC_ACQUIRE, __HIP_MEMORY_SCOPE_AGENT) < 8u)
        __builtin_amdgcn_s_sleep(4);
    }
  }
  __syncthreads();

  const u16* xrow = xsrc + (b0 + col) * KIN;
  bf16x8 ax[KKI], ah[4];
#pragma unroll
  for (int kk = 0; kk < KKI; ++kk)   // preload x(0)
    ax[kk] = *(const bf16x8*)(xrow + kk * 32 + quad * 8);

  for (int t = 0; t < T_SEQ; ++t) {
    const int cb = t & 1, nb = (t + 1) & 1;
    if (!PROD && t && (t & 3) == 0) {   // group-boundary sync only
      if (tid == 0) {
        u32 tgt = (u32)(t + 8 > T_SEQ ? T_SEQ : t + 8);
        while (__hip_atomic_load(flag, __ATOMIC_ACQUIRE, __HIP_MEMORY_SCOPE_AGENT) < tgt)
          __builtin_amdgcn_s_sleep(4);
      }
      __syncthreads();
    }
#pragma unroll
    for (int kk = 0; kk < 4; ++kk)
      ah[kk] = *(const bf16x8*)((const char*)&hbuf[cb][0] + col * 256 +
                                (((kk * 4 + quad) ^ col) << 4));
    f32x4 acc0 = {bias_t0, bias_t0, bias_t0, bias_t0};
    f32x4 acc1 = {bias_t1, bias_t1, bias_t1, bias_t1};
#pragma unroll
    for (int kk = 0; kk < KKI; ++kk) {
      acc0 = __builtin_amdgcn_mfma_f32_16x16x32_bf16(ax[kk], wih[0][kk], acc0, 0, 0, 0);
      acc1 = __builtin_amdgcn_mfma_f32_16x16x32_bf16(ax[kk], wih[1][kk], acc1, 0, 0, 0);
    }
    if (t + 1 < T_SEQ) {   // in-place prefetch x(t+1); consumer window covers it
      const u16* xn = xrow + BATCH * KIN;
#pragma unroll
      for (int kk = 0; kk < KKI; ++kk)
        ax[kk] = *(const bf16x8*)(xn + kk * 32 + quad * 8);
    }
#pragma unroll
    for (int kk = 0; kk < 4; ++kk) {
      acc0 = __builtin_amdgcn_mfma_f32_16x16x32_bf16(ah[kk], whh[0][kk], acc0, 0, 0, 0);
      acc1 = __builtin_amdgcn_mfma_f32_16x16x32_bf16(ah[kk], whh[1][kk], acc1, 0, 0, 0);
    }
    // validated exchange: lo lanes finish rows {0,1}, hi lanes {2,3}
#pragma unroll
    for (int rr = 0; rr < 2; ++rr) {
      float a_lo0 = acc0[rr], a_hi0 = acc0[2 + rr];
      float a_lo1 = acc1[rr], a_hi1 = acc1[2 + rr];
      float send0 = hi ? a_lo0 : a_hi0;
      float send1 = hi ? a_lo1 : a_hi1;
      float recv0 = __shfl_xor(send0, 8, 64);
      float recv1 = __shfl_xor(send1, 8, 64);
      float keep0 = hi ? a_hi0 : a_lo0;
      float keep1 = hi ? a_hi1 : a_lo1;
      float iv = hi ? recv0 : keep0;
      float fv = hi ? keep0 : recv0;
      float gv = hi ? recv1 : keep1;
      float ov = hi ? keep1 : recv1;
      float si = sigm(iv), sf = sigm(fv), tg = tanh_f(gv), so = sigm(ov);
      float cn = sf * cst[rr] + si * tg;
      cst[rr] = cn;
      hf[rr] = so * tanh_f(cn);
      int m = quad * 4 + rbase + rr;
      *(u16*)((char*)&hbuf[nb][0] + m * 256 + ((wave ^ m) << 4) + (col & 7) * 2) =
          f2bf(hf[rr]);
    }
    __syncthreads();
    if (PROD) {
      u32 v = hbuf[nb][wave * 64 + (((lane >> 2) ^ wave) << 2) + (lane & 3)];
      *(u32*)(y_out + (t * BATCH + b0 + wave) * HID + lane * 2) = v;
      // publish every 4 steps (R7-proven); barrier above drained steps <= t-1
      if (tid == 0 && (t & 3) == 3)
        __hip_atomic_store(flag, (u32)(t + 1), __ATOMIC_RELEASE, __HIP_MEMORY_SCOPE_AGENT);
    }
    xrow += BATCH * KIN;
  }
  if (PROD) {
    __syncthreads();   // drain final y stores
    if (tid == 0)
      __hip_atomic_store(flag, (u32)T_SEQ, __ATOMIC_RELEASE, __HIP_MEMORY_SCOPE_AGENT);
  }

  // ---- finals from fp32 registers ----
#pragma unroll
  for (int rr = 0; rr < 2; ++rr) {
    int m = quad * 4 + rbase + rr;
    dout[BATCH + LAYER * (BATCH * HID) + (b0 + m) * HID + jcol] = hf[rr];
    dout[BATCH + 2 * BATCH * HID + LAYER * (BATCH * HID) + (b0 + m) * HID + jcol] = cst[rr];
  }

  if (!PROD) {  // pred via fp32 LDS stage
#pragma unroll
    for (int rr = 0; rr < 2; ++rr)
      h32[quad * 4 + rbase + rr][jcol] = hf[rr];
    __syncthreads();
    float a0 = fmaxf(h32[wave][2 * lane], 0.f);
    float a1 = fmaxf(h32[wave][2 * lane + 1], 0.f);
    float p = a0 * post_w[2 * lane] + a1 * post_w[2 * lane + 1];
#pragma unroll
    for (int off = 32; off > 0; off >>= 1) p += __shfl_down(p, off, 64);
    if (lane == 0) dout[b0 + wave] = p + post_b[0];
  }
}

__global__ __launch_bounds__(1024, 4) void lstm_fused(
    const u16* __restrict__ xb,
    const u16* __restrict__ WcP, const u16* __restrict__ WhhP0,
    const float* __restrict__ bias0,
    const u16* __restrict__ WihP1, const u16* __restrict__ WhhP1,
    const float* __restrict__ bias1,
    const float* __restrict__ h0_in, const float* __restrict__ c0_in,
    u16* __restrict__ y0, u32* __restrict__ flags, float* __restrict__ dout,
    const float* __restrict__ post_w, const float* __restrict__ post_b) {
  __shared__ __align__(16) u32 hbuf[2][1024];
  __shared__ float h32[16][130];
  const int role = blockIdx.x >> 6;      // pairs (L0 b, L1 b) land on same XCD (64%8==0)
  const int blk = blockIdx.x & 63;
  const int b0 = blk * 16;
  if (role == 0)
    scan_role<2, true>(xb, WcP, WhhP0, bias0, h0_in, c0_in, y0, &flags[blk], dout,
                       post_w, post_b, b0, hbuf, h32);
  else
    scan_role<4, false>(y0, WihP1, WhhP1, bias1, h0_in, c0_in, y0, &flags[blk], dout,
                        post_w, post_b, b0, hbuf, h32);
}

extern "C" void kernel_launch(void* const* d_in, const int* in_sizes, int n_in,
                              void* d_out, int out_size, void* d_ws, size_t ws_size,
                              hipStream_t stream) {
  const float* x_in  = (const float*)d_in[0];
  const float* h0    = (const float*)d_in[1];
  const float* c0    = (const float*)d_in[2];
  const float* pre_w = (const float*)d_in[3];
  const float* pre_b = (const float*)d_in[4];
  const float* w_ih0 = (const float*)d_in[5];
  const float* w_hh0 = (const float*)d_in[6];
  const float* b_ih0 = (const float*)d_in[7];
  const float* b_hh0 = (const float*)d_in[8];
  const float* w_ih1 = (const float*)d_in[9];
  const float* w_hh1 = (const float*)d_in[10];
  const float* b_ih1 = (const float*)d_in[11];
  const float* b_hh1 = (const float*)d_in[12];
  const float* post_w = (const float*)d_in[13];
  const float* post_b = (const float*)d_in[14];
  float* out = (float*)d_out;
  char* ws = (char*)d_ws;

  u16*   WcP   = (u16*)(ws + 0);        // 65536 B
  u16*   WhhP0 = (u16*)(ws + 65536);    // 131072 B
  u16*   WihP1 = (u16*)(ws + 196608);   // 131072 B
  u16*   WhhP1 = (u16*)(ws + 327680);   // 131072 B
  float* bias0 = (float*)(ws + 458752); // 2048 B
  float* bias1 = (float*)(ws + 460800); // 2048 B
  u32*   flags = (u32*)(ws + 462848);   // 256 B
  u16*   xb    = (u16*)(ws + 463104);   // 33554432 B
  u16*   y0    = (u16*)(ws + 34017536); // 67108864 B

  conv_x_kernel<<<dim3(16384), dim3(256), 0, stream>>>(x_in, xb, flags);
  prep_kernel<<<dim3(256), dim3(256), 0, stream>>>(
      pre_w, pre_b, w_ih0, w_hh0, b_ih0, b_hh0, w_ih1, w_hh1, b_ih1, b_hh1,
      WcP, WhhP0, WihP1, WhhP1, bias0, bias1);
  lstm_fused<<<dim3(128), dim3(1024), 0, stream>>>(
      xb, WcP, WhhP0, bias0, WihP1, WhhP1, bias1, h0, c0, y0, flags, out,
      post_w, post_b);
}

// Round 10
// 758.248 us; speedup vs baseline: 1.3511x; 1.0070x over previous
//
#include <hip/hip_runtime.h>

typedef unsigned short u16;
typedef unsigned int   u32;
typedef short  bf16x8 __attribute__((ext_vector_type(8)));
typedef float  f32x4  __attribute__((ext_vector_type(4)));

#define T_SEQ 256
#define BATCH 1024
#define HID   128

__device__ __forceinline__ u16 f2bf(float f) {
  u32 x = __builtin_bit_cast(u32, f);
  x = x + 0x7fffu + ((x >> 16) & 1u);   // round-to-nearest-even
  return (u16)(x >> 16);
}
__device__ __forceinline__ float sigm(float x) {
  return __builtin_amdgcn_rcpf(1.0f + __expf(-x));
}
__device__ __forceinline__ float tanh_f(float x) {
  return 2.0f * __builtin_amdgcn_rcpf(1.0f + __expf(-2.0f * x)) - 1.0f;
}
// lane L <-> L^8 within each 16-lane row, on the VALU pipe (DPP row_ror:8).
// Bit-identical to __shfl_xor(v,8,64) here: R2 (this DPP) and R3 (shfl)
// produced byte-identical outputs on the same exchange.
__device__ __forceinline__ float dpp_xor8(float v) {
  int i = __builtin_bit_cast(int, v);
  i = __builtin_amdgcn_update_dpp(0, i, 0x128 /*row_ror:8*/, 0xf, 0xf, true);
  return __builtin_bit_cast(float, i);
}

// ---------------------------------------------------------------------------
// Convert x_in fp32 -> bf16 (4/thread) + zero the 64 producer->consumer flags.
// ---------------------------------------------------------------------------
__global__ void conv_x_kernel(const float* __restrict__ x_in, u16* __restrict__ xb,
                              u32* __restrict__ flags) {
  if (blockIdx.x == 0 && threadIdx.x < 64) flags[threadIdx.x] = 0;
  int i = (blockIdx.x * blockDim.x + threadIdx.x) * 4;
  float4 v = *(const float4*)(x_in + i);
  u32 lo = (u32)f2bf(v.x) | ((u32)f2bf(v.y) << 16);
  u32 hi = (u32)f2bf(v.z) | ((u32)f2bf(v.w) << 16);
  *(u32*)(xb + i) = lo;
  *(u32*)(xb + i + 2) = hi;
}

// ---------------------------------------------------------------------------
// Prep (PERMUTED gate layout — compute-validated R2-R4).
// Wave n owns h-cols [n*8,n*8+8): tile0 = i|f halves, tile1 = g|o halves.
//   col=lane&15, quad=lane>>4, gate t = tile*2+(col>>3), j=col&7
//   orig row r = t*128 + n*8 + j ; k = kk*32 + quad*8 + e
// WcP = w_ih0 @ pre_w (K=64, KK=2); bias0 = w_ih0@pre_b + b_ih0 + b_hh0.
// ---------------------------------------------------------------------------
__global__ void prep_kernel(const float* __restrict__ pre_w, const float* __restrict__ pre_b,
                            const float* __restrict__ w_ih0, const float* __restrict__ w_hh0,
                            const float* __restrict__ b_ih0, const float* __restrict__ b_hh0,
                            const float* __restrict__ w_ih1, const float* __restrict__ w_hh1,
                            const float* __restrict__ b_ih1, const float* __restrict__ b_hh1,
                            u16* __restrict__ WcP, u16* __restrict__ WhhP0,
                            u16* __restrict__ WihP1, u16* __restrict__ WhhP1,
                            float* __restrict__ bias0, float* __restrict__ bias1) {
  const int TOT = 230400;
  for (int idx = blockIdx.x * blockDim.x + threadIdx.x; idx < TOT;
       idx += gridDim.x * blockDim.x) {
    if (idx < 32768) {                       // WcP (KK=2)
      int e = idx & 7, lane = (idx >> 3) & 63, kk = (idx >> 9) & 1,
          tile = (idx >> 10) & 1, n = idx >> 11;
      int col = lane & 15, quad = lane >> 4;
      int r = (tile * 2 + (col >> 3)) * 128 + n * 8 + (col & 7);
      int k = kk * 32 + quad * 8 + e;
      float s = 0.f;
      for (int h = 0; h < 128; ++h)
        s += w_ih0[r * 128 + h] * pre_w[h * 64 + k];
      WcP[idx] = f2bf(s);
    } else if (idx < 33280) {                // bias0 permuted (fp32)
      int p = idx - 32768;
      int col = p & 15, tile = (p >> 4) & 1, n = p >> 5;
      int r = (tile * 2 + (col >> 3)) * 128 + n * 8 + (col & 7);
      float s = b_ih0[r] + b_hh0[r];
      for (int h = 0; h < 128; ++h)
        s += w_ih0[r * 128 + h] * pre_b[h];
      bias0[p] = s;
    } else if (idx < 229888) {               // 3 permuted bf16 copies (KK=4)
      int q = idx - 33280;
      int mat = q / 65536; q = q % 65536;
      int e = q & 7, lane = (q >> 3) & 63, kk = (q >> 9) & 3,
          tile = (q >> 11) & 1, n = q >> 12;
      int col = lane & 15, quad = lane >> 4;
      int r = (tile * 2 + (col >> 3)) * 128 + n * 8 + (col & 7);
      int k = kk * 32 + quad * 8 + e;
      const float* src = mat == 0 ? w_hh0 : (mat == 1 ? w_ih1 : w_hh1);
      u16* dst = mat == 0 ? WhhP0 : (mat == 1 ? WihP1 : WhhP1);
      dst[q] = f2bf(src[r * 128 + k]);
    } else {                                 // bias1 permuted (fp32)
      int p = idx - 229888;
      int col = p & 15, tile = (p >> 4) & 1, n = p >> 5;
      int r = (tile * 2 + (col >> 3)) * 128 + n * 8 + (col & 7);
      bias1[p] = b_ih1[r] + b_hh1[r];
    }
  }
}

// ---------------------------------------------------------------------------
// Fused pipelined 2-layer LSTM. 128 WGs: role = bid>>6 (0=L0 producer,
// 1=L1 consumer), blk = bid&63, 16 batch rows each. Weight-stationary
// (launch_bounds(1024,4) -> 128 VGPR/wave incl. AGPR half).
//  * y0 stores: plain coalesced u32 (R7-proven)
//  * producer publishes flag=t+1 at t%4==3 with RELEASE (wbL2 1x/4 steps)
//  * consumer polls with ACQUIRE only at t%4==0, requiring flag>=min(t+8,256)
//  * both roles prefetch x(t+1) IN-PLACE into ax (zero VGPR growth)
//  * gate exchange on VALU via DPP row_ror:8 (was ds_swizzle on LDS pipe)
// ---------------------------------------------------------------------------
template <int KKI, bool PROD>
__device__ __forceinline__ void scan_role(
    const u16* __restrict__ xsrc, const u16* __restrict__ WihF,
    const u16* __restrict__ WhhF, const float* __restrict__ biasP,
    const float* __restrict__ h0_in, const float* __restrict__ c0_in,
    u16* __restrict__ y_out, u32* flag, float* __restrict__ dout,
    const float* __restrict__ post_w, const float* __restrict__ post_b,
    int b0, u32 (*hbuf)[1024], float (*h32)[130]) {
  constexpr int KIN = KKI * 32;
  constexpr int LAYER = PROD ? 0 : 1;
  const int tid = threadIdx.x, wave = tid >> 6, lane = tid & 63;
  const int col = lane & 15, quad = lane >> 4;

  bf16x8 wih[2][KKI], whh[2][4];
#pragma unroll
  for (int t2 = 0; t2 < 2; ++t2)
#pragma unroll
    for (int kk = 0; kk < KKI; ++kk)
      wih[t2][kk] = *(const bf16x8*)(WihF + (((wave * 2 + t2) * KKI + kk) * 64 + lane) * 8);
#pragma unroll
  for (int t2 = 0; t2 < 2; ++t2)
#pragma unroll
    for (int kk = 0; kk < 4; ++kk)
      whh[t2][kk] = *(const bf16x8*)(WhhF + (((wave * 2 + t2) * 4 + kk) * 64 + lane) * 8);
  const float bias_t0 = biasP[wave * 32 + col];
  const float bias_t1 = biasP[wave * 32 + 16 + col];

  const int hi = col >> 3;          // lo lanes finish rows 0,1; hi lanes rows 2,3
  const int rbase = hi * 2;
  const int jcol = wave * 8 + (col & 7);

  float cst[2], hf[2];
#pragma unroll
  for (int rr = 0; rr < 2; ++rr) {
    cst[rr] = c0_in[(LAYER * BATCH + b0 + quad * 4 + rbase + rr) * HID + jcol];
    hf[rr]  = h0_in[(LAYER * BATCH + b0 + quad * 4 + rbase + rr) * HID + jcol];
  }

  {  // init hbuf[0] = h0 (swizzled bf16)
    const float* src = h0_in + (LAYER * BATCH + b0 + wave) * HID + lane * 2;
    u32 v = (u32)f2bf(src[0]) | ((u32)f2bf(src[1]) << 16);
    hbuf[0][wave * 64 + (((lane >> 2) ^ wave) << 2) + (lane & 3)] = v;
  }

  if (!PROD) {  // initial sync: producer must be >= 8 steps ahead
    if (tid == 0) {
      while (__hip_atomic_load(flag, __ATOMIC_ACQUIRE, __HIP_MEMORY_SCOPE_AGENT) < 8u)
        __builtin_amdgcn_s_sleep(4);
    }
  }
  __syncthreads();

  const u16* xrow = xsrc + (b0 + col) * KIN;
  bf16x8 ax[KKI], ah[4];
#pragma unroll
  for (int kk = 0; kk < KKI; ++kk)   // preload x(0)
    ax[kk] = *(const bf16x8*)(xrow + kk * 32 + quad * 8);

  for (int t = 0; t < T_SEQ; ++t) {
    const int cb = t & 1, nb = (t + 1) & 1;
    if (!PROD && t && (t & 3) == 0) {   // group-boundary sync only
      if (tid == 0) {
        u32 tgt = (u32)(t + 8 > T_SEQ ? T_SEQ : t + 8);
        while (__hip_atomic_load(flag, __ATOMIC_ACQUIRE, __HIP_MEMORY_SCOPE_AGENT) < tgt)
          __builtin_amdgcn_s_sleep(4);
      }
      __syncthreads();
    }
#pragma unroll
    for (int kk = 0; kk < 4; ++kk)
      ah[kk] = *(const bf16x8*)((const char*)&hbuf[cb][0] + col * 256 +
                                (((kk * 4 + quad) ^ col) << 4));
    f32x4 acc0 = {bias_t0, bias_t0, bias_t0, bias_t0};
    f32x4 acc1 = {bias_t1, bias_t1, bias_t1, bias_t1};
#pragma unroll
    for (int kk = 0; kk < KKI; ++kk) {
      acc0 = __builtin_amdgcn_mfma_f32_16x16x32_bf16(ax[kk], wih[0][kk], acc0, 0, 0, 0);
      acc1 = __builtin_amdgcn_mfma_f32_16x16x32_bf16(ax[kk], wih[1][kk], acc1, 0, 0, 0);
    }
    if (t + 1 < T_SEQ) {   // in-place prefetch x(t+1); consumer window covers it
      const u16* xn = xrow + BATCH * KIN;
#pragma unroll
      for (int kk = 0; kk < KKI; ++kk)
        ax[kk] = *(const bf16x8*)(xn + kk * 32 + quad * 8);
    }
#pragma unroll
    for (int kk = 0; kk < 4; ++kk) {
      acc0 = __builtin_amdgcn_mfma_f32_16x16x32_bf16(ah[kk], whh[0][kk], acc0, 0, 0, 0);
      acc1 = __builtin_amdgcn_mfma_f32_16x16x32_bf16(ah[kk], whh[1][kk], acc1, 0, 0, 0);
    }
    // validated exchange (DPP form): lo lanes finish rows {0,1}, hi {2,3}
#pragma unroll
    for (int rr = 0; rr < 2; ++rr) {
      float a_lo0 = acc0[rr], a_hi0 = acc0[2 + rr];
      float a_lo1 = acc1[rr], a_hi1 = acc1[2 + rr];
      float send0 = hi ? a_lo0 : a_hi0;
      float send1 = hi ? a_lo1 : a_hi1;
      float recv0 = dpp_xor8(send0);
      float recv1 = dpp_xor8(send1);
      float keep0 = hi ? a_hi0 : a_lo0;
      float keep1 = hi ? a_hi1 : a_lo1;
      float iv = hi ? recv0 : keep0;
      float fv = hi ? keep0 : recv0;
      float gv = hi ? recv1 : keep1;
      float ov = hi ? keep1 : recv1;
      float si = sigm(iv), sf = sigm(fv), tg = tanh_f(gv), so = sigm(ov);
      float cn = sf * cst[rr] + si * tg;
      cst[rr] = cn;
      hf[rr] = so * tanh_f(cn);
      int m = quad * 4 + rbase + rr;
      *(u16*)((char*)&hbuf[nb][0] + m * 256 + ((wave ^ m) << 4) + (col & 7) * 2) =
          f2bf(hf[rr]);
    }
    __syncthreads();
    if (PROD) {
      u32 v = hbuf[nb][wave * 64 + (((lane >> 2) ^ wave) << 2) + (lane & 3)];
      *(u32*)(y_out + (t * BATCH + b0 + wave) * HID + lane * 2) = v;
      // publish every 4 steps (R7-proven); barrier above drained steps <= t-1
      if (tid == 0 && (t & 3) == 3)
        __hip_atomic_store(flag, (u32)(t + 1), __ATOMIC_RELEASE, __HIP_MEMORY_SCOPE_AGENT);
    }
    xrow += BATCH * KIN;
  }
  if (PROD) {
    __syncthreads();   // drain final y stores
    if (tid == 0)
      __hip_atomic_store(flag, (u32)T_SEQ, __ATOMIC_RELEASE, __HIP_MEMORY_SCOPE_AGENT);
  }

  // ---- finals from fp32 registers ----
#pragma unroll
  for (int rr = 0; rr < 2; ++rr) {
    int m = quad * 4 + rbase + rr;
    dout[BATCH + LAYER * (BATCH * HID) + (b0 + m) * HID + jcol] = hf[rr];
    dout[BATCH + 2 * BATCH * HID + LAYER * (BATCH * HID) + (b0 + m) * HID + jcol] = cst[rr];
  }

  if (!PROD) {  // pred via fp32 LDS stage
#pragma unroll
    for (int rr = 0; rr < 2; ++rr)
      h32[quad * 4 + rbase + rr][jcol] = hf[rr];
    __syncthreads();
    float a0 = fmaxf(h32[wave][2 * lane], 0.f);
    float a1 = fmaxf(h32[wave][2 * lane + 1], 0.f);
    float p = a0 * post_w[2 * lane] + a1 * post_w[2 * lane + 1];
#pragma unroll
    for (int off = 32; off > 0; off >>= 1) p += __shfl_down(p, off, 64);
    if (lane == 0) dout[b0 + wave] = p + post_b[0];
  }
}

__global__ __launch_bounds__(1024, 4) void lstm_fused(
    const u16* __restrict__ xb,
    const u16* __restrict__ WcP, const u16* __restrict__ WhhP0,
    const float* __restrict__ bias0,
    const u16* __restrict__ WihP1, const u16* __restrict__ WhhP1,
    const float* __restrict__ bias1,
    const float* __restrict__ h0_in, const float* __restrict__ c0_in,
    u16* __restrict__ y0, u32* __restrict__ flags, float* __restrict__ dout,
    const float* __restrict__ post_w, const float* __restrict__ post_b) {
  __shared__ __align__(16) u32 hbuf[2][1024];
  __shared__ float h32[16][130];
  const int role = blockIdx.x >> 6;      // pairs (L0 b, L1 b) land on same XCD (64%8==0)
  const int blk = blockIdx.x & 63;
  const int b0 = blk * 16;
  if (role == 0)
    scan_role<2, true>(xb, WcP, WhhP0, bias0, h0_in, c0_in, y0, &flags[blk], dout,
                       post_w, post_b, b0, hbuf, h32);
  else
    scan_role<4, false>(y0, WihP1, WhhP1, bias1, h0_in, c0_in, y0, &flags[blk], dout,
                        post_w, post_b, b0, hbuf, h32);
}

extern "C" void kernel_launch(void* const* d_in, const int* in_sizes, int n_in,
                              void* d_out, int out_size, void* d_ws, size_t ws_size,
                              hipStream_t stream) {
  const float* x_in  = (const float*)d_in[0];
  const float* h0    = (const float*)d_in[1];
  const float* c0    = (const float*)d_in[2];
  const float* pre_w = (const float*)d_in[3];
  const float* pre_b = (const float*)d_in[4];
  const float* w_ih0 = (const float*)d_in[5];
  const float* w_hh0 = (const float*)d_in[6];
  const float* b_ih0 = (const float*)d_in[7];
  const float* b_hh0 = (const float*)d_in[8];
  const float* w_ih1 = (const float*)d_in[9];
  const float* w_hh1 = (const float*)d_in[10];
  const float* b_ih1 = (const float*)d_in[11];
  const float* b_hh1 = (const float*)d_in[12];
  const float* post_w = (const float*)d_in[13];
  const float* post_b = (const float*)d_in[14];
  float* out = (float*)d_out;
  char* ws = (char*)d_ws;

  u16*   WcP   = (u16*)(ws + 0);        // 65536 B
  u16*   WhhP0 = (u16*)(ws + 65536);    // 131072 B
  u16*   WihP1 = (u16*)(ws + 196608);   // 131072 B
  u16*   WhhP1 = (u16*)(ws + 327680);   // 131072 B
  float* bias0 = (float*)(ws + 458752); // 2048 B
  float* bias1 = (float*)(ws + 460800); // 2048 B
  u32*   flags = (u32*)(ws + 462848);   // 256 B
  u16*   xb    = (u16*)(ws + 463104);   // 33554432 B
  u16*   y0    = (u16*)(ws + 34017536); // 67108864 B

  conv_x_kernel<<<dim3(16384), dim3(256), 0, stream>>>(x_in, xb, flags);
  prep_kernel<<<dim3(256), dim3(256), 0, stream>>>(
      pre_w, pre_b, w_ih0, w_hh0, b_ih0, b_hh0, w_ih1, w_hh1, b_ih1, b_hh1,
      WcP, WhhP0, WihP1, WhhP1, bias0, bias1);
  lstm_fused<<<dim3(128), dim3(1024), 0, stream>>>(
      xb, WcP, WhhP0, bias0, WihP1, WhhP1, bias1, h0, c0, y0, flags, out,
      post_w, post_b);
}